// Round 1
// baseline (474.718 us; speedup 1.0000x reference)
//
#include <hip/hip_runtime.h>
#include <hip/hip_bf16.h>
#include <cstdint>
#include <cstddef>

// Problem: out[B,OUT] = (x * alpha) @ W,  W[i,o] = exp(-||col_i - row_o||^2)
// B=8192, IN=4096, OUT=4096, DIM=2.  All f32 in/out.
//
// Plan: kernel 1 builds Wt[o][i] = alpha[i]*exp(-d2) in bf16 (B^T layout) in d_ws
//       kernel 2 = bf16 MFMA GEMM (m97 structure: 128x128 tile, BK=32, 4 waves),
//                  A (=x f32) reg-staged with f32->bf16 convert into padded LDS,
//                  B staged via global_load_lds width=16 (linear LDS).

#define IN_DIM  4096
#define OUT_DIM 4096
#define BATCH   8192

#define BM 128
#define BN 128
#define BK 32
#define APAD 8              // A LDS row stride = 40 bf16 = 80B -> spreads banks

typedef __bf16 bf16x8 __attribute__((ext_vector_type(8)));
typedef float  f32x4  __attribute__((ext_vector_type(4)));

// ---------------------------------------------------------------------------
// Kernel 1: Wt[o][i] = alpha[i] * exp(-||c_i - r_o||^2), bf16, row-major [OUT][IN]
// ---------------------------------------------------------------------------
__global__ __launch_bounds__(256) void build_wt_kernel(
    const float* __restrict__ rows_mean,     // [OUT,2]
    const float* __restrict__ columns_mean,  // [IN,2]
    const float* __restrict__ alpha,         // [IN]
    __bf16* __restrict__ Wt)                 // [OUT][IN]
{
    const int o  = blockIdx.y;
    const int i0 = (blockIdx.x * 256 + threadIdx.x) * 8;

    const float r0 = rows_mean[2 * o];
    const float r1 = rows_mean[2 * o + 1];

    const float4* cm = (const float4*)(columns_mean + 2 * (size_t)i0);
    float4 c01 = cm[0], c23 = cm[1], c45 = cm[2], c67 = cm[3];
    const float4* ap = (const float4*)(alpha + i0);
    float4 a0 = ap[0], a1 = ap[1];

    float cx[8] = {c01.x, c01.z, c23.x, c23.z, c45.x, c45.z, c67.x, c67.z};
    float cy[8] = {c01.y, c01.w, c23.y, c23.w, c45.y, c45.w, c67.y, c67.w};
    float av[8] = {a0.x, a0.y, a0.z, a0.w, a1.x, a1.y, a1.z, a1.w};

    bf16x8 w;
#pragma unroll
    for (int j = 0; j < 8; ++j) {
        float d0 = cx[j] - r0;
        float d1 = cy[j] - r1;
        float d2 = d0 * d0 + d1 * d1;
        w[j] = (__bf16)(__expf(-d2) * av[j]);
    }
    *(bf16x8*)(Wt + (size_t)o * IN_DIM + i0) = w;
}

// ---------------------------------------------------------------------------
// Kernel 2: GEMM  Out[M,N] = X[M,K] @ Wt^T   (Wt is [N][K] bf16)
// ---------------------------------------------------------------------------
__device__ __forceinline__ void gload_lds16(const void* g, void* l) {
    __builtin_amdgcn_global_load_lds(
        (const __attribute__((address_space(1))) unsigned int*)g,
        (__attribute__((address_space(3))) unsigned int*)l, 16, 0, 0);
}

__global__ __launch_bounds__(256, 2) void gemm_kernel(
    const float*  __restrict__ X,    // [BATCH, IN]
    const __bf16* __restrict__ Wt,   // [OUT][IN]  (B^T: [N][K])
    float* __restrict__ Out)         // [BATCH, OUT]
{
    __shared__ __align__(16) __bf16 As[BM][BK + APAD];  // 10 KB
    __shared__ __align__(16) __bf16 Bs[BN][BK];         //  8 KB (linear for gload_lds)

    const int tid  = threadIdx.x;
    const int wave = tid >> 6;
    const int lane = tid & 63;
    const int wr = wave >> 1;            // wave row (0..1) -> 64 rows each
    const int wc = wave & 1;             // wave col (0..1) -> 64 cols each
    const int lr = lane & 15;
    const int lk = (lane >> 4) << 3;     // k-offset 0,8,16,24

    const int n0 = blockIdx.x * BN;
    const int m0 = blockIdx.y * BM;

    // A staging: thread t loads 16 f32 of row (t>>1), k-half (t&1)
    const int ar = tid >> 1;
    const int ak = (tid & 1) << 4;
    const float* aP = X + (size_t)(m0 + ar) * IN_DIM + ak;

    // B staging via global_load_lds: call0 rows 0..63, call1 rows 64..127
    const int br = tid >> 2;             // 0..63
    const int bo = (tid & 3) << 3;       // bf16 offset in row (16B chunks)
    const __bf16* bP0 = Wt + (size_t)(n0 + br) * IN_DIM + bo;
    const __bf16* bP1 = bP0 + (size_t)64 * IN_DIM;
    __bf16* bL0 = &Bs[0][0] + wave * 512;          // wave-uniform LDS base (1KB/wave)
    __bf16* bL1 = &Bs[0][0] + 64 * BK + wave * 512;

    f32x4 acc[4][4];
#pragma unroll
    for (int m = 0; m < 4; ++m)
#pragma unroll
        for (int n = 0; n < 4; ++n)
            acc[m][n] = f32x4{0.f, 0.f, 0.f, 0.f};

    const int kTiles = IN_DIM / BK;
    for (int kt = 0; kt < kTiles; ++kt) {
        // issue A global loads early (overlap with prev compute tail)
        float4 v0 = *(const float4*)(aP + 0);
        float4 v1 = *(const float4*)(aP + 4);
        float4 v2 = *(const float4*)(aP + 8);
        float4 v3 = *(const float4*)(aP + 12);
        aP += BK;

        __syncthreads();   // previous tile's ds_reads complete before overwrite

        bf16x8 p0, p1;
        p0[0] = (__bf16)v0.x; p0[1] = (__bf16)v0.y; p0[2] = (__bf16)v0.z; p0[3] = (__bf16)v0.w;
        p0[4] = (__bf16)v1.x; p0[5] = (__bf16)v1.y; p0[6] = (__bf16)v1.z; p0[7] = (__bf16)v1.w;
        p1[0] = (__bf16)v2.x; p1[1] = (__bf16)v2.y; p1[2] = (__bf16)v2.z; p1[3] = (__bf16)v2.w;
        p1[4] = (__bf16)v3.x; p1[5] = (__bf16)v3.y; p1[6] = (__bf16)v3.z; p1[7] = (__bf16)v3.w;
        *(bf16x8*)&As[ar][ak]     = p0;
        *(bf16x8*)&As[ar][ak + 8] = p1;

        gload_lds16(bP0, bL0);
        gload_lds16(bP1, bL1);
        bP0 += BK;
        bP1 += BK;

        __syncthreads();   // compiler drains vmcnt+lgkmcnt before barrier

        bf16x8 af[4], bf[4];
#pragma unroll
        for (int m = 0; m < 4; ++m)
            af[m] = *(const bf16x8*)&As[wr * 64 + m * 16 + lr][lk];
#pragma unroll
        for (int n = 0; n < 4; ++n)
            bf[n] = *(const bf16x8*)&Bs[wc * 64 + n * 16 + lr][lk];

#pragma unroll
        for (int m = 0; m < 4; ++m)
#pragma unroll
            for (int n = 0; n < 4; ++n)
                acc[m][n] = __builtin_amdgcn_mfma_f32_16x16x32_bf16(
                    af[m], bf[n], acc[m][n], 0, 0, 0);
    }

    // Epilogue: C/D layout (m89-verified): col = lane&15, row = (lane>>4)*4 + j
    const int crow0 = m0 + wr * 64 + ((lane >> 4) << 2);
    const int ccol0 = n0 + wc * 64 + (lane & 15);
#pragma unroll
    for (int m = 0; m < 4; ++m)
#pragma unroll
        for (int n = 0; n < 4; ++n) {
            float* o = Out + (size_t)(crow0 + m * 16) * OUT_DIM + (ccol0 + n * 16);
#pragma unroll
            for (int j = 0; j < 4; ++j)
                o[(size_t)j * OUT_DIM] = acc[m][n][j];
        }
}

// ---------------------------------------------------------------------------
extern "C" void kernel_launch(void* const* d_in, const int* in_sizes, int n_in,
                              void* d_out, int out_size, void* d_ws, size_t ws_size,
                              hipStream_t stream) {
    const float* x  = (const float*)d_in[0];   // [8192, 4096]
    const float* rm = (const float*)d_in[1];   // [4096, 2]
    const float* cm = (const float*)d_in[2];   // [4096, 2]
    const float* al = (const float*)d_in[3];   // [4096]
    float* out = (float*)d_out;                // [8192, 4096]

    __bf16* Wt = (__bf16*)d_ws;                // 4096*4096*2 = 32 MiB scratch

    dim3 g1(IN_DIM / (256 * 8), OUT_DIM);      // (2, 4096)
    build_wt_kernel<<<g1, 256, 0, stream>>>(rm, cm, al, Wt);

    dim3 g2(OUT_DIM / BN, BATCH / BM);         // (32, 64)
    gemm_kernel<<<g2, 256, 0, stream>>>(x, Wt, out);
}

// Round 2
// 343.018 us; speedup vs baseline: 1.3839x; 1.3839x over previous
//
#include <hip/hip_runtime.h>
#include <hip/hip_bf16.h>
#include <cstdint>
#include <cstddef>

// out[B,OUT] = (x * alpha) @ W,  W[i,o] = exp(-||col_i - row_o||^2)
// B=8192, IN=4096, OUT=4096.  f32 in/out.
//
// Pipeline:
//   k0: convert x f32 -> bf16 Xb            (d_ws + 32MB, 64 MB)
//   k1: Wt[o][i] = alpha[i]*exp(-d2), bf16  (d_ws, 32 MB)  [B^T layout]
//   k2: 256x256 8-phase counted-vmcnt bf16 MFMA GEMM (T1+T2+T3+T4+T5)
//
// GEMM schedule (per K-tile BK=64, 4 phases; 2 LDS buffers of 1 K-tile each):
//   LDS layout per buf: A[4 slices][256 rows][16 cols] + B likewise; slice = 16 k's.
//   Stage unit u = {A slice u, B slice u} = 2 gload_lds/thread.
//   Phase q of iter t:  q0: read(kk0, n01) stage Kt+1.u2->buf^1
//                       q1: read(kk0, n23) stage Kt+1.u3->buf^1
//                       q2: read(kk1, n01) stage Kt+2.u0->buf
//                       q3: read(kk1, n23) stage Kt+2.u1->buf
//   Each phase: ds_reads; stage; vmcnt(6); s_barrier; lgkmcnt(0); 16 MFMA (setprio 1); s_barrier.
//   vmcnt(6) = 3 units in flight; unit staged at phase X is confirmed at X+3's wait,
//   first read at X+4 (RAW ok); stage targets are regions dead since >=1 barrier (WAR ok).
//   Swizzle: 16B chunk c holds linear chunk c ^ ((c>>3)&1)  (== byte ^ ((byte>>7)&1)<<4):
//   fragment reads (16 lanes, rows stride 32B) spread 8 slots x 2 lanes -> 2-way = free.

#define IN_DIM  4096
#define OUT_DIM 4096
#define BATCH   8192

#define BM 256
#define BN 256
#define BK 64
#define KTILES (IN_DIM / BK)   // 64
#define THREADS 512

#define SLICE  4096            // elems per k-slice (256 rows * 16)
#define OPOFF  16384           // A -> B offset (4 slices)
#define BUFOFF 32768           // elems per buffer (A + B)

typedef __bf16 bf16x8 __attribute__((ext_vector_type(8)));
typedef float  f32x4  __attribute__((ext_vector_type(4)));

// ---------------------------------------------------------------------------
__global__ __launch_bounds__(256) void convert_x_kernel(
    const float* __restrict__ x, __bf16* __restrict__ xb)
{
    const size_t i = ((size_t)blockIdx.x * 256 + threadIdx.x) * 8;
    const float4 v0 = *(const float4*)(x + i);
    const float4 v1 = *(const float4*)(x + i + 4);
    bf16x8 o;
    o[0] = (__bf16)v0.x; o[1] = (__bf16)v0.y; o[2] = (__bf16)v0.z; o[3] = (__bf16)v0.w;
    o[4] = (__bf16)v1.x; o[5] = (__bf16)v1.y; o[6] = (__bf16)v1.z; o[7] = (__bf16)v1.w;
    *(bf16x8*)(xb + i) = o;
}

// ---------------------------------------------------------------------------
__global__ __launch_bounds__(256) void build_wt_kernel(
    const float* __restrict__ rows_mean,     // [OUT,2]
    const float* __restrict__ columns_mean,  // [IN,2]
    const float* __restrict__ alpha,         // [IN]
    __bf16* __restrict__ Wt)                 // [OUT][IN]
{
    const int o  = blockIdx.y;
    const int i0 = (blockIdx.x * 256 + threadIdx.x) * 8;

    const float r0 = rows_mean[2 * o];
    const float r1 = rows_mean[2 * o + 1];

    const float4* cm = (const float4*)(columns_mean + 2 * (size_t)i0);
    float4 c01 = cm[0], c23 = cm[1], c45 = cm[2], c67 = cm[3];
    const float4* ap = (const float4*)(alpha + i0);
    float4 a0 = ap[0], a1 = ap[1];

    float cx[8] = {c01.x, c01.z, c23.x, c23.z, c45.x, c45.z, c67.x, c67.z};
    float cy[8] = {c01.y, c01.w, c23.y, c23.w, c45.y, c45.w, c67.y, c67.w};
    float av[8] = {a0.x, a0.y, a0.z, a0.w, a1.x, a1.y, a1.z, a1.w};

    bf16x8 w;
#pragma unroll
    for (int j = 0; j < 8; ++j) {
        float d0 = cx[j] - r0;
        float d1 = cy[j] - r1;
        w[j] = (__bf16)(__expf(-(d0 * d0 + d1 * d1)) * av[j]);
    }
    *(bf16x8*)(Wt + (size_t)o * IN_DIM + i0) = w;
}

// ---------------------------------------------------------------------------
__global__ __launch_bounds__(THREADS, 2) void gemm_kernel(
    const __bf16* __restrict__ Xb,   // [BATCH, IN] bf16
    const __bf16* __restrict__ Wt,   // [OUT][IN]   bf16 (B^T)
    float* __restrict__ Out)         // [BATCH, OUT]
{
    __shared__ __align__(16) __bf16 lds[2 * BUFOFF];   // 128 KiB

    const int tid  = threadIdx.x;
    const int wave = tid >> 6;
    const int lane = tid & 63;
    const int lh   = lane >> 4;          // 0..3
    const int lr   = lane & 15;
    const int wm   = wave >> 2;          // 0..1  (M waves)
    const int wn   = wave & 3;           // 0..3  (N waves)

    // ---- XCD-aware block swizzle (512 wg, 512%8==0 -> simple bijection) ----
    const int nwg  = (BATCH / BM) * (OUT_DIM / BN);          // 512
    const int swz  = (blockIdx.x & 7) * (nwg >> 3) + (blockIdx.x >> 3);
    const int m0   = (swz >> 4) * BM;                        // 32 m-tiles
    const int n0   = (swz & 15) * BN;                        // 16 n-tiles

    // ---- staging addresses (pre-swizzled global source, linear LDS dest) ----
    const int g    = tid ^ ((tid >> 3) & 1);   // swizzled 16B chunk id
    const int grow = g >> 1;                   // 0..255
    const int gc8  = (g & 1) * 8;
    const __bf16* gA = Xb + (size_t)(m0 + grow) * IN_DIM + gc8;
    const __bf16* gB = Wt + (size_t)(n0 + grow) * IN_DIM + gc8;
    __bf16* sA = lds + wave * 512;             // wave-uniform LDS dest bases
    __bf16* sB = lds + OPOFF + wave * 512;

    auto STAGE = [&](int kt, int u, int b) {
        const __bf16* ga = gA + (size_t)kt * BK + u * 16;
        const __bf16* gb = gB + (size_t)kt * BK + u * 16;
        __builtin_amdgcn_global_load_lds(
            (const __attribute__((address_space(1))) unsigned int*)ga,
            (__attribute__((address_space(3))) unsigned int*)(sA + b * BUFOFF + u * SLICE),
            16, 0, 0);
        __builtin_amdgcn_global_load_lds(
            (const __attribute__((address_space(1))) unsigned int*)gb,
            (__attribute__((address_space(3))) unsigned int*)(sB + b * BUFOFF + u * SLICE),
            16, 0, 0);
    };

    // ---- fragment read bases (swizzled) ----
    const int c8x = ((lh & 1) * 8) ^ (((lr >> 2) & 1) << 3);
    const __bf16* aRd = lds + (lh >> 1) * SLICE + (wm * 128 + lr) * 16 + c8x;
    const __bf16* bRd = lds + OPOFF + (lh >> 1) * SLICE + (wn * 64 + lr) * 16 + c8x;

    f32x4 acc[8][4];
#pragma unroll
    for (int m = 0; m < 8; ++m)
#pragma unroll
        for (int n = 0; n < 4; ++n)
            acc[m][n] = f32x4{0.f, 0.f, 0.f, 0.f};

    // ---- prologue: K0 all units -> buf0, K1 u0,u1 -> buf1 ----
    STAGE(0, 0, 0); STAGE(0, 1, 0); STAGE(0, 2, 0); STAGE(0, 3, 0);
    STAGE(1, 0, 1); STAGE(1, 1, 1);
    asm volatile("s_waitcnt vmcnt(4)" ::: "memory");
    __builtin_amdgcn_s_barrier();

    bf16x8 af[8];

    for (int t = 0; t < KTILES; ++t) {
        const int buf = t & 1;
        const int bo  = buf * BUFOFF;

        // ================= phase 0: kk=0, n={0,1} =================
        {
#pragma unroll
            for (int m = 0; m < 8; ++m)
                af[m] = *(const bf16x8*)(aRd + bo + m * 256);
            bf16x8 b0 = *(const bf16x8*)(bRd + bo + 0 * 256);
            bf16x8 b1 = *(const bf16x8*)(bRd + bo + 1 * 256);
            if (t + 1 < KTILES) STAGE(t + 1, 2, buf ^ 1);
            asm volatile("s_waitcnt vmcnt(6)" ::: "memory");
            __builtin_amdgcn_s_barrier();
            asm volatile("s_waitcnt lgkmcnt(0)" ::: "memory");
            __builtin_amdgcn_sched_barrier(0);
            __builtin_amdgcn_s_setprio(1);
#pragma unroll
            for (int m = 0; m < 8; ++m) {
                acc[m][0] = __builtin_amdgcn_mfma_f32_16x16x32_bf16(af[m], b0, acc[m][0], 0, 0, 0);
                acc[m][1] = __builtin_amdgcn_mfma_f32_16x16x32_bf16(af[m], b1, acc[m][1], 0, 0, 0);
            }
            __builtin_amdgcn_s_setprio(0);
            __builtin_amdgcn_sched_barrier(0);
            __builtin_amdgcn_s_barrier();
        }
        // ================= phase 1: kk=0, n={2,3} =================
        {
            bf16x8 b2 = *(const bf16x8*)(bRd + bo + 2 * 256);
            bf16x8 b3 = *(const bf16x8*)(bRd + bo + 3 * 256);
            if (t + 1 < KTILES) STAGE(t + 1, 3, buf ^ 1);
            asm volatile("s_waitcnt vmcnt(6)" ::: "memory");
            __builtin_amdgcn_s_barrier();
            asm volatile("s_waitcnt lgkmcnt(0)" ::: "memory");
            __builtin_amdgcn_sched_barrier(0);
            __builtin_amdgcn_s_setprio(1);
#pragma unroll
            for (int m = 0; m < 8; ++m) {
                acc[m][2] = __builtin_amdgcn_mfma_f32_16x16x32_bf16(af[m], b2, acc[m][2], 0, 0, 0);
                acc[m][3] = __builtin_amdgcn_mfma_f32_16x16x32_bf16(af[m], b3, acc[m][3], 0, 0, 0);
            }
            __builtin_amdgcn_s_setprio(0);
            __builtin_amdgcn_sched_barrier(0);
            __builtin_amdgcn_s_barrier();
        }
        // ================= phase 2: kk=1, n={0,1} =================
        {
#pragma unroll
            for (int m = 0; m < 8; ++m)
                af[m] = *(const bf16x8*)(aRd + bo + 2 * SLICE + m * 256);
            bf16x8 b0 = *(const bf16x8*)(bRd + bo + 2 * SLICE + 0 * 256);
            bf16x8 b1 = *(const bf16x8*)(bRd + bo + 2 * SLICE + 1 * 256);
            if (t + 2 < KTILES) STAGE(t + 2, 0, buf);
            asm volatile("s_waitcnt vmcnt(6)" ::: "memory");
            __builtin_amdgcn_s_barrier();
            asm volatile("s_waitcnt lgkmcnt(0)" ::: "memory");
            __builtin_amdgcn_sched_barrier(0);
            __builtin_amdgcn_s_setprio(1);
#pragma unroll
            for (int m = 0; m < 8; ++m) {
                acc[m][0] = __builtin_amdgcn_mfma_f32_16x16x32_bf16(af[m], b0, acc[m][0], 0, 0, 0);
                acc[m][1] = __builtin_amdgcn_mfma_f32_16x16x32_bf16(af[m], b1, acc[m][1], 0, 0, 0);
            }
            __builtin_amdgcn_s_setprio(0);
            __builtin_amdgcn_sched_barrier(0);
            __builtin_amdgcn_s_barrier();
        }
        // ================= phase 3: kk=1, n={2,3} =================
        {
            bf16x8 b2 = *(const bf16x8*)(bRd + bo + 2 * SLICE + 2 * 256);
            bf16x8 b3 = *(const bf16x8*)(bRd + bo + 2 * SLICE + 3 * 256);
            if (t + 2 < KTILES) STAGE(t + 2, 1, buf);
            asm volatile("s_waitcnt vmcnt(6)" ::: "memory");
            __builtin_amdgcn_s_barrier();
            asm volatile("s_waitcnt lgkmcnt(0)" ::: "memory");
            __builtin_amdgcn_sched_barrier(0);
            __builtin_amdgcn_s_setprio(1);
#pragma unroll
            for (int m = 0; m < 8; ++m) {
                acc[m][2] = __builtin_amdgcn_mfma_f32_16x16x32_bf16(af[m], b2, acc[m][2], 0, 0, 0);
                acc[m][3] = __builtin_amdgcn_mfma_f32_16x16x32_bf16(af[m], b3, acc[m][3], 0, 0, 0);
            }
            __builtin_amdgcn_s_setprio(0);
            __builtin_amdgcn_sched_barrier(0);
            __builtin_amdgcn_s_barrier();
        }
    }

    // ---- epilogue: C/D layout col=lane&15, row=(lane>>4)*4+j ----
    const int crow = m0 + wm * 128 + lh * 4;
    const int ccol = n0 + wn * 64 + lr;
#pragma unroll
    for (int m = 0; m < 8; ++m)
#pragma unroll
        for (int n = 0; n < 4; ++n) {
            float* o = Out + (size_t)(crow + m * 16) * OUT_DIM + (ccol + n * 16);
#pragma unroll
            for (int j = 0; j < 4; ++j)
                o[(size_t)j * OUT_DIM] = acc[m][n][j];
        }
}

// ---------------------------------------------------------------------------
extern "C" void kernel_launch(void* const* d_in, const int* in_sizes, int n_in,
                              void* d_out, int out_size, void* d_ws, size_t ws_size,
                              hipStream_t stream) {
    const float* x  = (const float*)d_in[0];   // [8192, 4096]
    const float* rm = (const float*)d_in[1];   // [4096, 2]
    const float* cm = (const float*)d_in[2];   // [4096, 2]
    const float* al = (const float*)d_in[3];   // [4096]
    float* out = (float*)d_out;                // [8192, 4096]

    __bf16* Wt = (__bf16*)d_ws;                                  // 32 MiB
    __bf16* Xb = (__bf16*)((char*)d_ws + (size_t)32 * 1024 * 1024); // 64 MiB

    convert_x_kernel<<<BATCH * IN_DIM / (256 * 8), 256, 0, stream>>>(x, Xb);

    dim3 g1(IN_DIM / (256 * 8), OUT_DIM);      // (2, 4096)
    build_wt_kernel<<<g1, 256, 0, stream>>>(rm, cm, al, Wt);

    dim3 g2((BATCH / BM) * (OUT_DIM / BN));    // 512
    gemm_kernel<<<g2, THREADS, 0, stream>>>(Xb, Wt, out);
}